// Round 1
// baseline (126.175 us; speedup 1.0000x reference)
//
#include <hip/hip_runtime.h>
#include <hip/hip_bf16.h>
#include <stdint.h>

#define N 8192
#define FIN 128
#define H 64
#define QB 16
#define MB 128
#define NIT (N / MB)

typedef __attribute__((ext_vector_type(8))) short short8;
typedef __attribute__((ext_vector_type(4))) float f32x4;

#define MFMA16(a, b, c) __builtin_amdgcn_mfma_f32_16x16x32_bf16(a, b, c, 0, 0, 0)

typedef __attribute__((address_space(1))) const void* gas_p;
typedef __attribute__((address_space(3))) void* las_p;

static __device__ __forceinline__ void load_lds16(const void* g, void* l) {
    __builtin_amdgcn_global_load_lds((gas_p)g, (las_p)l, 16, 0, 0);
}

static __device__ __forceinline__ unsigned short f2bf(float f) {
    unsigned int u = __float_as_uint(f);
    unsigned int r = (u + 0x7FFFu + ((u >> 16) & 1u)) >> 16;
    return (unsigned short)r;
}

// -------- kernel 1: projection  seq[8192,128] @ W[128,64] -> Q(=V), K in bf16 --------
__global__ __launch_bounds__(256) void proj_kernel(const float* __restrict__ seq,
                                                   const float* __restrict__ W1,
                                                   const float* __restrict__ W2,
                                                   unsigned short* __restrict__ Qb,
                                                   unsigned short* __restrict__ Kb) {
    __shared__ float srow[4][FIN];
    const int r0 = blockIdx.x * 4;
    const int tid = threadIdx.x;
    for (int i = tid; i < 4 * FIN; i += 256) srow[i >> 7][i & 127] = seq[(size_t)r0 * FIN + i];
    __syncthreads();
    const int w = tid >> 6, lane = tid & 63;
    const float* s = srow[w];
    float q = 0.f, k = 0.f;
#pragma unroll 8
    for (int f = 0; f < FIN; ++f) {
        const float sv = s[f];
        q += sv * W1[f * H + lane];
        k += sv * W2[f * H + lane];
    }
    const int r = r0 + w;
    Qb[r * H + lane] = f2bf(q);
    Kb[r * H + lane] = f2bf(k);
}

// -------- kernel 2: transpose Qb[8192,64] -> QT[64,8192] (bf16) --------
__global__ __launch_bounds__(256) void tr_kernel(const unsigned short* __restrict__ Qb,
                                                 unsigned short* __restrict__ QT) {
    __shared__ unsigned short t[64][65];
    const int m0 = blockIdx.x * 64;
    const int tid = threadIdx.x;
    for (int i = tid; i < 64 * 64; i += 256) {
        const int m = i >> 6, h = i & 63;
        t[h][m] = Qb[(size_t)(m0 + m) * H + h];
    }
    __syncthreads();
    for (int i = tid; i < 64 * 64; i += 256) {
        const int h = i >> 6, m = i & 63;
        QT[(size_t)h * N + m0 + m] = t[h][m];
    }
}

// -------- kernel 3: flash attention, deferred normalization --------
// block: 256 thr (4 waves). QB=16 query rows per block, MB=128 keys per iter,
// each wave owns a 32-key slice. mfma 16x16x32 bf16 for QK^T and PV.
__global__ __launch_bounds__(256) void flash_kernel(const unsigned short* __restrict__ Qb,
                                                    const unsigned short* __restrict__ Kb,
                                                    const unsigned short* __restrict__ QT,
                                                    const float* __restrict__ bias,
                                                    float* __restrict__ out) {
    __shared__ unsigned short Kt[MB * H];       // 16KB, [m][k] rows 128B, XOR-swizzled
    __shared__ unsigned short Vt[H * MB];       // 16KB, V^T tile [h][m] rows 256B, XOR-swizzled
    __shared__ unsigned short Pt[4][16 * 40];   // per-wave P [q][m], stride 40 ushorts (80B)
    __shared__ float redv[4][16][65];
    __shared__ float redd[4][16];

    const int tid = threadIdx.x;
    const int w = tid >> 6, lane = tid & 63;
    const int g = lane >> 4, c = lane & 15;
    const int q0 = blockIdx.x * QB;
    const int mwoff = w * 32;  // this wave's key offset within the MB tile

    // Q A-fragments (row = c, k = g*8+j), K dim = 64 -> 2 frags
    short8 qf0, qf1;
    {
        const unsigned short* qrow = Qb + (size_t)(q0 + c) * H + g * 8;
        qf0 = *(const short8*)(qrow);
        qf1 = *(const short8*)(qrow + 32);
    }

    f32x4 vals[4] = {};             // PV accum, 4 h-tiles; D row=q(g*4+r), col=h(ht*16+c)
    float dsum[4] = {0.f, 0.f, 0.f, 0.f};

    // prefetch bias for iter 0 (rows q0+g*4+r, col m0+mwoff+t*16+c)
    float bv[8];
#pragma unroll
    for (int t = 0; t < 2; ++t)
#pragma unroll
        for (int r = 0; r < 4; ++r)
            bv[t * 4 + r] = bias[(size_t)(q0 + g * 4 + r) * N + (mwoff + t * 16 + c)];

    for (int it = 0; it < NIT; ++it) {
        const int m0 = it * MB;
        __syncthreads();  // previous tile fully consumed before restage
        // stage K tile (16KB) and V^T tile (16KB); LDS linear dest, source pre-swizzled
        {
            char* kbase = (char*)Kt + w * 4096;
            char* vbase = (char*)Vt + w * 4096;
#pragma unroll
            for (int i = 0; i < 4; ++i) {
                {
                    const int off = w * 4096 + i * 1024 + lane * 16;
                    const int row = off >> 7;          // m
                    const int colb = off & 127;
                    const int srcb = colb ^ ((row & 7) << 4);
                    load_lds16((const char*)Kb + (size_t)(m0 + row) * 128 + srcb, kbase + i * 1024);
                }
                {
                    const int off = w * 4096 + i * 1024 + lane * 16;
                    const int h = off >> 8;            // h row of V^T
                    const int colb = off & 255;
                    const int srcb = colb ^ ((h & 7) << 4);
                    load_lds16((const char*)QT + (size_t)h * (N * 2) + m0 * 2 + srcb, vbase + i * 1024);
                }
            }
        }
        __syncthreads();

        // issue next iter's bias prefetch, keep current in bcur
        float bcur[8];
#pragma unroll
        for (int i = 0; i < 8; ++i) bcur[i] = bv[i];
        if (it + 1 < NIT) {
            const size_t mnext = (size_t)(m0 + MB);
#pragma unroll
            for (int t = 0; t < 2; ++t)
#pragma unroll
                for (int r = 0; r < 4; ++r)
                    bv[t * 4 + r] = bias[(size_t)(q0 + g * 4 + r) * N + mnext + (mwoff + t * 16 + c)];
        }

        // ---- QK^T for the wave's 16x32 slice, 2 col-tiles ----
        unsigned short pw[8];
#pragma unroll
        for (int t = 0; t < 2; ++t) {
            const int m = mwoff + t * 16 + c;  // tile-local key index (B-frag col=c)
            const char* kb = (const char*)Kt + m * 128;
            const int sw = (m & 7) << 4;
            const short8 kf0 = *(const short8*)(kb + ((g * 16) ^ sw));
            const short8 kf1 = *(const short8*)(kb + ((64 + g * 16) ^ sw));
            f32x4 acc = {};
            acc = MFMA16(qf0, kf0, acc);
            acc = MFMA16(qf1, kf1, acc);
#pragma unroll
            for (int r = 0; r < 4; ++r) {
                const float p = __expf(acc[r] * 0.125f) * bcur[t * 4 + r];
                dsum[r] += p;
                pw[t * 4 + r] = f2bf(p);
            }
        }

        // ---- P -> wave-local LDS (stride 40 ushorts, conflict-free), read A-frag ----
        {
            unsigned short* pp = (unsigned short*)Pt[w];
#pragma unroll
            for (int t = 0; t < 2; ++t)
#pragma unroll
                for (int r = 0; r < 4; ++r)
                    pp[(g * 4 + r) * 40 + t * 16 + c] = pw[t * 4 + r];
        }
        __builtin_amdgcn_wave_barrier();
        const short8 pa = *(const short8*)((unsigned short*)Pt[w] + c * 40 + g * 8);

        // ---- PV: vals[ht] += P(16x32) @ V(32x16) ----
#pragma unroll
        for (int ht = 0; ht < 4; ++ht) {
            const int h = ht * 16 + c;  // B-frag col=c -> output h
            const char* vb = (const char*)Vt + h * 256;
            const short8 vf = *(const short8*)(vb + (((mwoff + g * 8) * 2) ^ ((h & 7) << 4)));
            vals[ht] = MFMA16(pa, vf, vals[ht]);
        }
    }

    // ---- reduce denominator across the 16 c-lanes ----
#pragma unroll
    for (int r = 0; r < 4; ++r) {
        float v = dsum[r];
        v += __shfl_xor(v, 1);
        v += __shfl_xor(v, 2);
        v += __shfl_xor(v, 4);
        v += __shfl_xor(v, 8);
        dsum[r] = v;
    }
    // ---- cross-wave reduction in LDS ----
#pragma unroll
    for (int ht = 0; ht < 4; ++ht)
#pragma unroll
        for (int r = 0; r < 4; ++r)
            redv[w][g * 4 + r][ht * 16 + c] = vals[ht][r];
    if (c == 0) {
#pragma unroll
        for (int r = 0; r < 4; ++r) redd[w][g * 4 + r] = dsum[r];
    }
    __syncthreads();

    const int h = tid & 63;
    for (int qq = tid >> 6; qq < QB; qq += 4) {
        const float v = redv[0][qq][h] + redv[1][qq][h] + redv[2][qq][h] + redv[3][qq][h];
        const float d = redd[0][qq] + redd[1][qq] + redd[2][qq] + redd[3][qq];
        const float x = v / (d + 1e-19f);
        out[(size_t)(q0 + qq) * H + h] = x > 0.f ? x : expm1f(x);
    }
}

extern "C" void kernel_launch(void* const* d_in, const int* in_sizes, int n_in,
                              void* d_out, int out_size, void* d_ws, size_t ws_size,
                              hipStream_t stream) {
    const float* seq  = (const float*)d_in[0];
    const float* bias = (const float*)d_in[1];
    const float* W1   = (const float*)d_in[2];
    const float* W2   = (const float*)d_in[3];
    // d_in[4] = bias_zero (all zeros) -- folded out
    float* out = (float*)d_out;

    unsigned short* Qb = (unsigned short*)d_ws;   // N*H bf16 = 1 MB  (also V)
    unsigned short* Kb = Qb + (size_t)N * H;      // 1 MB
    unsigned short* QT = Kb + (size_t)N * H;      // 1 MB (V^T)

    proj_kernel<<<N / 4, 256, 0, stream>>>(seq, W1, W2, Qb, Kb);
    tr_kernel<<<N / 64, 256, 0, stream>>>(Qb, QT);
    flash_kernel<<<N / QB, 256, 0, stream>>>(Qb, Kb, QT, bias, out);
}